// Round 9
// baseline (442.557 us; speedup 1.0000x reference)
//
#include <hip/hip_runtime.h>
#include <math.h>

#define HW_N 65536   // H*W
#define NCH 64       // channels
#define NB 8         // batch
#define NBINS 256
#define NBAND 512    // NB*NCH

// d_ws float-offset layout
#define WS_MIN   0      // [512] band min
#define WS_MAX   512    // [512] band max
#define WS_SUM   1024   // [512] band sum
#define WS_PFG   2048   // [512] band foreground proportion
#define WS_MEANS 2560   // [512] per-band mean of normalized band
#define WS_LO    3072   // [8] low_end
#define WS_HI    3080   // [8] high_end
#define WS_W     3088   // [512] w[n][c]  (n*64+c)
#define WS_PMIN  3600   // [64] per-(i,n) min of relu'd einsum
#define WS_PMAX  3664   // [64] per-(i,n) max

// ---- parallel Otsu: inclusive scan of hist & hist*bc + first-argmax ----
// Mirrors reference: var12[i] = w1[i]*w2[i+1]*(m1[i]-m2[i+1])^2, strict '>'
// first-argmax (tree tie-break to smaller index == first occurrence).
__device__ int otsu_argmax(float* sh, float* shb, float* sv, int* si, int t) {
    for (int o = 1; o < NBINS; o <<= 1) {
        float a = 0.f, b = 0.f;
        if (t < NBINS) {
            a = sh[t]; b = shb[t];
            if (t >= o) { a += sh[t - o]; b += shb[t - o]; }
        }
        __syncthreads();
        if (t < NBINS) { sh[t] = a; shb[t] = b; }
        __syncthreads();
    }
    float N = sh[NBINS - 1], HB = shb[NBINS - 1];
    if (t < NBINS) {
        float v = -INFINITY;
        if (t < NBINS - 1) {
            float w1 = sh[t], w2 = N - w1;       // counts: integer-exact
            float m1 = shb[t] / fmaxf(w1, 1e-12f);
            float m2 = (HB - shb[t]) / fmaxf(w2, 1e-12f);
            float d = m1 - m2;
            v = (w1 * w2) * (d * d);
        }
        sv[t] = v; si[t] = t;
    }
    __syncthreads();
    for (int o = NBINS / 2; o; o >>= 1) {
        if (t < o) {
            float vo = sv[t + o]; int io = si[t + o];
            if (vo > sv[t] || (vo == sv[t] && io < si[t])) { sv[t] = vo; si[t] = io; }
        }
        __syncthreads();
    }
    return si[0];
}

// K1: per-band min / max / sum.  grid 512, block 1024.
__global__ __launch_bounds__(1024) void band_stats(const float* __restrict__ x,
                                                   float* __restrict__ ws) {
    int b = blockIdx.x;
    int t = threadIdx.x;
    const float4* p = (const float4*)(x + (size_t)b * HW_N);
    float mn = INFINITY, mx = -INFINITY, sum = 0.f;
#pragma unroll 4
    for (int k = t; k < HW_N / 4; k += 1024) {
        float4 v = p[k];
        mn = fminf(mn, fminf(fminf(v.x, v.y), fminf(v.z, v.w)));
        mx = fmaxf(mx, fmaxf(fmaxf(v.x, v.y), fmaxf(v.z, v.w)));
        sum += (v.x + v.y) + (v.z + v.w);
    }
    for (int o = 32; o; o >>= 1) {
        mn = fminf(mn, __shfl_down(mn, o));
        mx = fmaxf(mx, __shfl_down(mx, o));
        sum += __shfl_down(sum, o);
    }
    __shared__ float smn[16], smx[16], ssm[16];
    int wave = t >> 6, lane = t & 63;
    if (lane == 0) { smn[wave] = mn; smx[wave] = mx; ssm[wave] = sum; }
    __syncthreads();
    if (t == 0) {
        mn = smn[0]; mx = smx[0]; sum = ssm[0];
        for (int k = 1; k < 16; ++k) {
            mn = fminf(mn, smn[k]);
            mx = fmaxf(mx, smx[k]);
            sum += ssm[k];
        }
        ws[WS_MIN + b] = mn;
        ws[WS_MAX + b] = mx;
        ws[WS_SUM + b] = sum;
    }
}

// K2: per-image otsu over 64 band-means + variance -> low/high ends.
// grid 8, block 256.
__global__ __launch_bounds__(256) void image_otsu(float* __restrict__ ws) {
    int img = blockIdx.x;
    int t = threadIdx.x;
    __shared__ float sh[NBINS], shb[NBINS], sv[NBINS];
    __shared__ int si[NBINS];
    __shared__ float sred[4];

    float m = 0.f;
    if (t < NCH) {
        int b = img * NCH + t;
        float mn = ws[WS_MIN + b], mx = ws[WS_MAX + b], sum = ws[WS_SUM + b];
        float rng = mx - mn;
        m = (rng != 0.f) ? ((sum * (1.f / HW_N) - mn) / rng) : 0.f;
        ws[WS_MEANS + b] = m;
    }
    if (t < 64) {   // NCH == 64 == one wave
        float mmn = m, mmx = m, msum = m;
        for (int o = 32; o; o >>= 1) {
            mmn = fminf(mmn, __shfl_down(mmn, o));
            mmx = fmaxf(mmx, __shfl_down(mmx, o));
            msum += __shfl_down(msum, o);
        }
        if (t == 0) { sred[0] = mmn; sred[1] = mmx; sred[2] = msum; }
    }
    if (t < NBINS) sh[t] = 0.f;
    __syncthreads();
    float mmn = sred[0], mmx = sred[1];
    float mbar = sred[2] * (1.f / NCH);
    if (t < 64) {
        float d = m - mbar;
        float sq = d * d;
        for (int o = 32; o; o >>= 1) sq += __shfl_down(sq, o);
        if (t == 0) sred[3] = sq * (1.f / NCH);   // means.var() (ddof=0)
    }
    float rngm = mmx - mmn;
    float width = rngm * (1.f / NBINS);
    float safe_w = (width > 0.f) ? width : 1.f;
    if (t < 64) {
        int idx = (int)floorf((m - mmn) / safe_w);
        idx = min(max(idx, 0), NBINS - 1);
        atomicAdd(&sh[idx], 1.f);
    }
    __syncthreads();
    if (t < NBINS) shb[t] = sh[t] * (mmn + (t + 0.5f) * width);
    __syncthreads();
    int bi = otsu_argmax(sh, shb, sv, si, t);
    if (t == 0) {
        float var = sred[3];
        float thr = mmn + (bi + 0.5f) * width;
        ws[WS_LO + img] = (thr > 0.1f) ? (thr - var) : thr;
        ws[WS_HI + img] = thr + var;
    }
}

// K3: per-band otsu + foreground proportion, ONE data pass.
// Packed 64-bit LDS atomic: low32 = bin count, high32 = count of fn*256 >
// idx+0.5 (exact: counts <= 65536, no carry into high word).
// pfg*N = (N - cumsum[bi]) + above[bi].  grid 512, block 1024.
__global__ __launch_bounds__(1024) void band_otsu_pfg(const float* __restrict__ x,
                                                      float* __restrict__ ws) {
    int b = blockIdx.x;
    int t = threadIdx.x;
    float mn = ws[WS_MIN + b], mx = ws[WS_MAX + b];
    float rng = mx - mn;
    __shared__ unsigned long long h64[NBINS];
    __shared__ float sh[NBINS], shb[NBINS], sv[NBINS];
    __shared__ int si[NBINS];
    if (t < NBINS) h64[t] = 0ull;
    __syncthreads();

    const float4* px = (const float4*)(x + (size_t)b * HW_N);
    if (rng != 0.f) {
        float inv256 = 256.f / rng;
#pragma unroll 4
        for (int k = t; k < HW_N / 4; k += 1024) {
            float4 v = px[k];
            float s0 = (v.x - mn) * inv256;
            float s1 = (v.y - mn) * inv256;
            float s2 = (v.z - mn) * inv256;
            float s3 = (v.w - mn) * inv256;
            int i0 = min((int)s0, NBINS - 1);
            int i1 = min((int)s1, NBINS - 1);
            int i2 = min((int)s2, NBINS - 1);
            int i3 = min((int)s3, NBINS - 1);
            atomicAdd(&h64[i0], 1ull | ((unsigned long long)(s0 > i0 + 0.5f) << 32));
            atomicAdd(&h64[i1], 1ull | ((unsigned long long)(s1 > i1 + 0.5f) << 32));
            atomicAdd(&h64[i2], 1ull | ((unsigned long long)(s2 > i2 + 0.5f) << 32));
            atomicAdd(&h64[i3], 1ull | ((unsigned long long)(s3 > i3 + 0.5f) << 32));
        }
    } else if (t == 0) {
        h64[0] = (unsigned long long)HW_N;   // all normalized values exactly 0
    }
    __syncthreads();
    float width = (rng != 0.f) ? (1.f / NBINS) : 0.f;
    if (t < NBINS) {
        float h = (float)(unsigned)(h64[t] & 0xffffffffull);
        sh[t] = h;
        shb[t] = h * ((t + 0.5f) * width);   // bc in normalized space (mn_f = 0)
    }
    __syncthreads();
    int bi = otsu_argmax(sh, shb, sv, si, t);
    if (t == 0) {
        float N = sh[NBINS - 1];
        float above = (float)(unsigned)(h64[bi] >> 32);
        float cnt = (N - sh[bi]) + above;    // integer-exact floats
        ws[WS_PFG + b] = cnt * (1.f / HW_N);
    }
}

// K4: w[n][c] decision + init per-pair min/max slots.  grid 1, block 512.
__global__ __launch_bounds__(512) void compute_w(float* __restrict__ ws) {
    int t = threadIdx.x;           // t = n*64 + c
    int n = t >> 6;
    float m   = ws[WS_MEANS + t];
    float pfg = ws[WS_PFG + t];
    float lo  = ws[WS_LO + n];
    float hi  = ws[WS_HI + n];
    float wv = (m >= hi && pfg > 0.2f) ? -1.f
             : ((m <= lo && pfg < 0.1f) ? 1.f : 0.f);
    ws[WS_W + t] = wv;
    if (t < 64) {
        ws[WS_PMIN + t] = INFINITY;
        ws[WS_PMAX + t] = 0.f;     // relu output is >= 0
    }
}

// K5: y[i,n,p] = relu(255 * sum_c w[n,c]*fn(x[i,c,p])), per-(i,n) min/max.
// 2 px/thread (float2), grid 1024 (8 img x 128 chunks) -> 4096 waves =
// 16 waves/CU; 8-channel groups = 8 independent 8B loads in flight.
__global__ __launch_bounds__(256) void einsum_relu(const float* __restrict__ x,
                                                   float* __restrict__ ws,
                                                   float* __restrict__ out) {
    int img = blockIdx.x >> 7;
    int chunk = blockIdx.x & 127;
    int t = threadIdx.x;
    __shared__ float4 wt0[NCH], wt1[NCH];   // wt0[c]={w[0..3][c]}, wt1[c]={w[4..7][c]}
    __shared__ float2 cp[NCH];              // (mn_c, inv_c)
    if (t < NCH) {
        int b = img * NCH + t;
        float mn = ws[WS_MIN + b];
        float rng = ws[WS_MAX + b] - mn;
        cp[t] = make_float2(mn, (rng != 0.f) ? (1.f / rng) : 0.f);
        wt0[t] = make_float4(ws[WS_W + 0 * NCH + t], ws[WS_W + 1 * NCH + t],
                             ws[WS_W + 2 * NCH + t], ws[WS_W + 3 * NCH + t]);
        wt1[t] = make_float4(ws[WS_W + 4 * NCH + t], ws[WS_W + 5 * NCH + t],
                             ws[WS_W + 6 * NCH + t], ws[WS_W + 7 * NCH + t]);
    }
    __syncthreads();

    const int Q2 = HW_N / 2;                // float2s per channel (32768)
    int q = chunk * 256 + t;                // this thread's pixel-pair
    const float2* px = (const float2*)x + (size_t)img * NCH * Q2 + q;

    float2 acc0, acc1, acc2, acc3, acc4, acc5, acc6, acc7;
    acc0 = acc1 = acc2 = acc3 = acc4 = acc5 = acc6 = acc7 = make_float2(0.f, 0.f);

#define PROC2(v, ci)                                                           \
    {                                                                          \
        float2 pc = cp[ci];                                                    \
        float4 w0 = wt0[ci], w1 = wt1[ci];                                     \
        float fx = (v.x - pc.x) * pc.y, fy = (v.y - pc.x) * pc.y;              \
        acc0.x = fmaf(w0.x, fx, acc0.x); acc0.y = fmaf(w0.x, fy, acc0.y);      \
        acc1.x = fmaf(w0.y, fx, acc1.x); acc1.y = fmaf(w0.y, fy, acc1.y);      \
        acc2.x = fmaf(w0.z, fx, acc2.x); acc2.y = fmaf(w0.z, fy, acc2.y);      \
        acc3.x = fmaf(w0.w, fx, acc3.x); acc3.y = fmaf(w0.w, fy, acc3.y);      \
        acc4.x = fmaf(w1.x, fx, acc4.x); acc4.y = fmaf(w1.x, fy, acc4.y);      \
        acc5.x = fmaf(w1.y, fx, acc5.x); acc5.y = fmaf(w1.y, fy, acc5.y);      \
        acc6.x = fmaf(w1.z, fx, acc6.x); acc6.y = fmaf(w1.z, fy, acc6.y);      \
        acc7.x = fmaf(w1.w, fx, acc7.x); acc7.y = fmaf(w1.w, fy, acc7.y);      \
    }

    for (int c = 0; c < NCH; c += 8) {
        float2 v0 = px[(size_t)(c + 0) * Q2];
        float2 v1 = px[(size_t)(c + 1) * Q2];
        float2 v2 = px[(size_t)(c + 2) * Q2];
        float2 v3 = px[(size_t)(c + 3) * Q2];
        float2 v4 = px[(size_t)(c + 4) * Q2];
        float2 v5 = px[(size_t)(c + 5) * Q2];
        float2 v6 = px[(size_t)(c + 6) * Q2];
        float2 v7 = px[(size_t)(c + 7) * Q2];
        PROC2(v0, c + 0)
        PROC2(v1, c + 1)
        PROC2(v2, c + 2)
        PROC2(v3, c + 3)
        PROC2(v4, c + 4)
        PROC2(v5, c + 5)
        PROC2(v6, c + 6)
        PROC2(v7, c + 7)
    }
#undef PROC2

    float2* out2 = (float2*)out + (size_t)img * NB * Q2 + q;
    float tmin[NB], tmax[NB];
    float2 accs[NB] = {acc0, acc1, acc2, acc3, acc4, acc5, acc6, acc7};
#pragma unroll
    for (int n = 0; n < NB; ++n) {
        float2 a = accs[n];
        float2 y;
        y.x = fmaxf(a.x * 255.f, 0.f);
        y.y = fmaxf(a.y * 255.f, 0.f);
        out2[(size_t)n * Q2] = y;
        tmin[n] = fminf(y.x, y.y);
        tmax[n] = fmaxf(y.x, y.y);
    }
#pragma unroll
    for (int n = 0; n < NB; ++n) {
        for (int o = 32; o; o >>= 1) {
            tmin[n] = fminf(tmin[n], __shfl_down(tmin[n], o));
            tmax[n] = fmaxf(tmax[n], __shfl_down(tmax[n], o));
        }
    }
    if ((t & 63) == 0) {
#pragma unroll
        for (int n = 0; n < NB; ++n) {
            // nonneg floats: int ordering == float ordering
            atomicMin((int*)&ws[WS_PMIN + img * NB + n], __float_as_int(tmin[n]));
            atomicMax((int*)&ws[WS_PMAX + img * NB + n], __float_as_int(tmax[n]));
        }
    }
}

// K6: in-place per-(i,n) min-max normalize * 255.  grid 1024, block 256.
__global__ __launch_bounds__(256) void norm_out(float* __restrict__ out,
                                                const float* __restrict__ ws) {
    int pair = blockIdx.x >> 4;
    int t = threadIdx.x;
    float mnp = ws[WS_PMIN + pair];
    float rng = ws[WS_PMAX + pair] - mnp;
    float4* p = (float4*)out + (size_t)pair * (HW_N / 4) + (size_t)(blockIdx.x & 15) * 1024;
    if (rng != 0.f) {
        float inv = 255.f / rng;
#pragma unroll
        for (int k = 0; k < 4; ++k) {
            float4 v = p[k * 256 + t];
            v.x = (v.x - mnp) * inv;
            v.y = (v.y - mnp) * inv;
            v.z = (v.z - mnp) * inv;
            v.w = (v.w - mnp) * inv;
            p[k * 256 + t] = v;
        }
    } else {
        float4 z = make_float4(0.f, 0.f, 0.f, 0.f);
#pragma unroll
        for (int k = 0; k < 4; ++k) p[k * 256 + t] = z;
    }
}

extern "C" void kernel_launch(void* const* d_in, const int* in_sizes, int n_in,
                              void* d_out, int out_size, void* d_ws, size_t ws_size,
                              hipStream_t stream) {
    const float* x = (const float*)d_in[0];
    float* out = (float*)d_out;
    float* ws = (float*)d_ws;
    band_stats<<<NBAND, 1024, 0, stream>>>(x, ws);
    image_otsu<<<NB, 256, 0, stream>>>(ws);
    band_otsu_pfg<<<NBAND, 1024, 0, stream>>>(x, ws);
    compute_w<<<1, 512, 0, stream>>>(ws);
    einsum_relu<<<1024, 256, 0, stream>>>(x, ws, out);
    norm_out<<<1024, 256, 0, stream>>>(out, ws);
}

// Round 11
// 347.263 us; speedup vs baseline: 1.2744x; 1.2744x over previous
//
#include <hip/hip_runtime.h>
#include <math.h>

#define HW_N 65536   // H*W
#define NCH 64       // channels
#define NB 8         // batch
#define NBINS 256
#define NBAND 512    // NB*NCH

// d_ws float-offset layout
#define WS_MIN   0      // [512] band min
#define WS_MAX   512    // [512] band max
#define WS_SUM   1024   // [512] band sum
#define WS_PFG   2048   // [512] band foreground proportion
#define WS_MEANS 2560   // [512] per-band mean of normalized band
#define WS_LO    3072   // [8] low_end
#define WS_HI    3080   // [8] high_end
#define WS_W     3088   // [512] w[n][c]  (n*64+c)
#define WS_PMIN  3600   // [64] per-(i,n) min of relu'd einsum
#define WS_PMAX  3664   // [64] per-(i,n) max

// ---- parallel Otsu: inclusive scan of hist & hist*bc + first-argmax ----
// Mirrors reference: var12[i] = w1[i]*w2[i+1]*(m1[i]-m2[i+1])^2, strict '>'
// first-argmax (tree tie-break to smaller index == first occurrence).
__device__ int otsu_argmax(float* sh, float* shb, float* sv, int* si, int t) {
    for (int o = 1; o < NBINS; o <<= 1) {
        float a = 0.f, b = 0.f;
        if (t < NBINS) {
            a = sh[t]; b = shb[t];
            if (t >= o) { a += sh[t - o]; b += shb[t - o]; }
        }
        __syncthreads();
        if (t < NBINS) { sh[t] = a; shb[t] = b; }
        __syncthreads();
    }
    float N = sh[NBINS - 1], HB = shb[NBINS - 1];
    if (t < NBINS) {
        float v = -INFINITY;
        if (t < NBINS - 1) {
            float w1 = sh[t], w2 = N - w1;       // counts: integer-exact
            float m1 = shb[t] / fmaxf(w1, 1e-12f);
            float m2 = (HB - shb[t]) / fmaxf(w2, 1e-12f);
            float d = m1 - m2;
            v = (w1 * w2) * (d * d);
        }
        sv[t] = v; si[t] = t;
    }
    __syncthreads();
    for (int o = NBINS / 2; o; o >>= 1) {
        if (t < o) {
            float vo = sv[t + o]; int io = si[t + o];
            if (vo > sv[t] || (vo == sv[t] && io < si[t])) { sv[t] = vo; si[t] = io; }
        }
        __syncthreads();
    }
    return si[0];
}

// K1: per-band min / max / sum.  grid 512, block 1024.
// Two-buffer register prefetch (4 x float4 in flight) + sched_barrier pin:
// the compiler otherwise re-rolls grouped loads into serial load->use chains
// (observed VGPR_Count=32, 420-800 GB/s latency-bound).
__global__ __launch_bounds__(1024) void band_stats(const float* __restrict__ x,
                                                   float* __restrict__ ws) {
    int b = blockIdx.x;
    int t = threadIdx.x;
    const float4* p = (const float4*)(x + (size_t)b * HW_N);
    float mn = INFINITY, mx = -INFINITY, sum = 0.f;

#define K1_RED(v)                                                              \
    {                                                                          \
        mn = fminf(mn, fminf(fminf(v.x, v.y), fminf(v.z, v.w)));               \
        mx = fmaxf(mx, fmaxf(fmaxf(v.x, v.y), fmaxf(v.z, v.w)));               \
        sum += (v.x + v.y) + (v.z + v.w);                                      \
    }

    float4 buf[4];
#pragma unroll
    for (int j = 0; j < 4; ++j) buf[j] = p[t + j * 1024];
    for (int g = 1; g < 4; ++g) {
        float4 nb[4];
#pragma unroll
        for (int j = 0; j < 4; ++j) nb[j] = p[t + (g * 4 + j) * 1024];
        __builtin_amdgcn_sched_barrier(0);
#pragma unroll
        for (int j = 0; j < 4; ++j) K1_RED(buf[j]);
#pragma unroll
        for (int j = 0; j < 4; ++j) buf[j] = nb[j];
    }
#pragma unroll
    for (int j = 0; j < 4; ++j) K1_RED(buf[j]);
#undef K1_RED

    for (int o = 32; o; o >>= 1) {
        mn = fminf(mn, __shfl_down(mn, o));
        mx = fmaxf(mx, __shfl_down(mx, o));
        sum += __shfl_down(sum, o);
    }
    __shared__ float smn[16], smx[16], ssm[16];
    int wave = t >> 6, lane = t & 63;
    if (lane == 0) { smn[wave] = mn; smx[wave] = mx; ssm[wave] = sum; }
    __syncthreads();
    if (t == 0) {
        mn = smn[0]; mx = smx[0]; sum = ssm[0];
        for (int k = 1; k < 16; ++k) {
            mn = fminf(mn, smn[k]);
            mx = fmaxf(mx, smx[k]);
            sum += ssm[k];
        }
        ws[WS_MIN + b] = mn;
        ws[WS_MAX + b] = mx;
        ws[WS_SUM + b] = sum;
    }
}

// K2: per-image otsu over 64 band-means + variance -> low/high ends.
// grid 8, block 256.
__global__ __launch_bounds__(256) void image_otsu(float* __restrict__ ws) {
    int img = blockIdx.x;
    int t = threadIdx.x;
    __shared__ float sh[NBINS], shb[NBINS], sv[NBINS];
    __shared__ int si[NBINS];
    __shared__ float sred[4];

    float m = 0.f;
    if (t < NCH) {
        int b = img * NCH + t;
        float mn = ws[WS_MIN + b], mx = ws[WS_MAX + b], sum = ws[WS_SUM + b];
        float rng = mx - mn;
        m = (rng != 0.f) ? ((sum * (1.f / HW_N) - mn) / rng) : 0.f;
        ws[WS_MEANS + b] = m;
    }
    if (t < 64) {   // NCH == 64 == one wave
        float mmn = m, mmx = m, msum = m;
        for (int o = 32; o; o >>= 1) {
            mmn = fminf(mmn, __shfl_down(mmn, o));
            mmx = fmaxf(mmx, __shfl_down(mmx, o));
            msum += __shfl_down(msum, o);
        }
        if (t == 0) { sred[0] = mmn; sred[1] = mmx; sred[2] = msum; }
    }
    if (t < NBINS) sh[t] = 0.f;
    __syncthreads();
    float mmn = sred[0], mmx = sred[1];
    float mbar = sred[2] * (1.f / NCH);
    if (t < 64) {
        float d = m - mbar;
        float sq = d * d;
        for (int o = 32; o; o >>= 1) sq += __shfl_down(sq, o);
        if (t == 0) sred[3] = sq * (1.f / NCH);   // means.var() (ddof=0)
    }
    float rngm = mmx - mmn;
    float width = rngm * (1.f / NBINS);
    float safe_w = (width > 0.f) ? width : 1.f;
    if (t < 64) {
        int idx = (int)floorf((m - mmn) / safe_w);
        idx = min(max(idx, 0), NBINS - 1);
        atomicAdd(&sh[idx], 1.f);
    }
    __syncthreads();
    if (t < NBINS) shb[t] = sh[t] * (mmn + (t + 0.5f) * width);
    __syncthreads();
    int bi = otsu_argmax(sh, shb, sv, si, t);
    if (t == 0) {
        float var = sred[3];
        float thr = mmn + (bi + 0.5f) * width;
        ws[WS_LO + img] = (thr > 0.1f) ? (thr - var) : thr;
        ws[WS_HI + img] = thr + var;
    }
}

// K3: per-band otsu + foreground proportion, ONE data pass, prefetched.
// Packed 64-bit LDS atomic: low32 = bin count, high32 = count of fn*256 >
// idx+0.5 (exact: counts <= 65536).  pfg*N = (N - cumsum[bi]) + above[bi].
// grid 512, block 1024.
__global__ __launch_bounds__(1024) void band_otsu_pfg(const float* __restrict__ x,
                                                      float* __restrict__ ws) {
    int b = blockIdx.x;
    int t = threadIdx.x;
    float mn = ws[WS_MIN + b], mx = ws[WS_MAX + b];
    float rng = mx - mn;
    __shared__ unsigned long long h64[NBINS];
    __shared__ float sh[NBINS], shb[NBINS], sv[NBINS];
    __shared__ int si[NBINS];
    if (t < NBINS) h64[t] = 0ull;
    __syncthreads();

    const float4* px = (const float4*)(x + (size_t)b * HW_N);
    if (rng != 0.f) {
        float inv256 = 256.f / rng;
#define K3_HIST(v)                                                             \
    {                                                                          \
        float s0 = (v.x - mn) * inv256;                                        \
        float s1 = (v.y - mn) * inv256;                                        \
        float s2 = (v.z - mn) * inv256;                                        \
        float s3 = (v.w - mn) * inv256;                                        \
        int i0 = min((int)s0, NBINS - 1);                                      \
        int i1 = min((int)s1, NBINS - 1);                                      \
        int i2 = min((int)s2, NBINS - 1);                                      \
        int i3 = min((int)s3, NBINS - 1);                                      \
        atomicAdd(&h64[i0], 1ull | ((unsigned long long)(s0 > i0 + 0.5f) << 32)); \
        atomicAdd(&h64[i1], 1ull | ((unsigned long long)(s1 > i1 + 0.5f) << 32)); \
        atomicAdd(&h64[i2], 1ull | ((unsigned long long)(s2 > i2 + 0.5f) << 32)); \
        atomicAdd(&h64[i3], 1ull | ((unsigned long long)(s3 > i3 + 0.5f) << 32)); \
    }
        float4 buf[4];
#pragma unroll
        for (int j = 0; j < 4; ++j) buf[j] = px[t + j * 1024];
        for (int g = 1; g < 4; ++g) {
            float4 nb[4];
#pragma unroll
            for (int j = 0; j < 4; ++j) nb[j] = px[t + (g * 4 + j) * 1024];
            __builtin_amdgcn_sched_barrier(0);
#pragma unroll
            for (int j = 0; j < 4; ++j) K3_HIST(buf[j]);
#pragma unroll
            for (int j = 0; j < 4; ++j) buf[j] = nb[j];
        }
#pragma unroll
        for (int j = 0; j < 4; ++j) K3_HIST(buf[j]);
#undef K3_HIST
    } else if (t == 0) {
        h64[0] = (unsigned long long)HW_N;   // all normalized values exactly 0
    }
    __syncthreads();
    float width = (rng != 0.f) ? (1.f / NBINS) : 0.f;
    if (t < NBINS) {
        float h = (float)(unsigned)(h64[t] & 0xffffffffull);
        sh[t] = h;
        shb[t] = h * ((t + 0.5f) * width);   // bc in normalized space (mn_f = 0)
    }
    __syncthreads();
    int bi = otsu_argmax(sh, shb, sv, si, t);
    if (t == 0) {
        float N = sh[NBINS - 1];
        float above = (float)(unsigned)(h64[bi] >> 32);
        float cnt = (N - sh[bi]) + above;    // integer-exact floats
        ws[WS_PFG + b] = cnt * (1.f / HW_N);
    }
}

// K4: w[n][c] decision + init per-pair min/max slots.  grid 1, block 512.
__global__ __launch_bounds__(512) void compute_w(float* __restrict__ ws) {
    int t = threadIdx.x;           // t = n*64 + c
    int n = t >> 6;
    float m   = ws[WS_MEANS + t];
    float pfg = ws[WS_PFG + t];
    float lo  = ws[WS_LO + n];
    float hi  = ws[WS_HI + n];
    float wv = (m >= hi && pfg > 0.2f) ? -1.f
             : ((m <= lo && pfg < 0.1f) ? 1.f : 0.f);
    ws[WS_W + t] = wv;
    if (t < 64) {
        ws[WS_PMIN + t] = INFINITY;
        ws[WS_PMAX + t] = 0.f;     // relu output is >= 0
    }
}

// K5: y[i,n,p] = relu(255 * sum_c w[n,c]*fn(x[i,c,p])), per-(i,n) min/max.
// float4 per thread (4 px), 16-channel two-buffer register prefetch:
// 16 x 16B loads in flight while 16 PROCs (~1280 cyc) run -> HBM latency
// fully hidden per wave.  grid 512 (8 img x 64 chunks), block 256
// (2 blocks/CU; VGPR up to 256 harmless at this grid).
__global__ __launch_bounds__(256) void einsum_relu(const float* __restrict__ x,
                                                   float* __restrict__ ws,
                                                   float* __restrict__ out) {
    int img = blockIdx.x >> 6;
    int chunk = blockIdx.x & 63;
    int t = threadIdx.x;
    __shared__ float4 wt0[NCH], wt1[NCH];   // wt0[c]={w[0..3][c]}, wt1[c]={w[4..7][c]}
    __shared__ float2 cp[NCH];              // (mn_c, inv_c)
    if (t < NCH) {
        int b = img * NCH + t;
        float mn = ws[WS_MIN + b];
        float rng = ws[WS_MAX + b] - mn;
        cp[t] = make_float2(mn, (rng != 0.f) ? (1.f / rng) : 0.f);
        wt0[t] = make_float4(ws[WS_W + 0 * NCH + t], ws[WS_W + 1 * NCH + t],
                             ws[WS_W + 2 * NCH + t], ws[WS_W + 3 * NCH + t]);
        wt1[t] = make_float4(ws[WS_W + 4 * NCH + t], ws[WS_W + 5 * NCH + t],
                             ws[WS_W + 6 * NCH + t], ws[WS_W + 7 * NCH + t]);
    }
    __syncthreads();

    const int Q = HW_N / 4;                 // float4s per channel
    int q = chunk * 256 + t;                // this thread's pixel-quad
    const float4* px = (const float4*)x + (size_t)img * NCH * Q + q;

    float4 acc0, acc1, acc2, acc3, acc4, acc5, acc6, acc7;
    acc0 = acc1 = acc2 = acc3 = acc4 = acc5 = acc6 = acc7 = make_float4(0.f, 0.f, 0.f, 0.f);

#define PROC(v, ci)                                                            \
    {                                                                          \
        float2 pc = cp[ci];                                                    \
        float4 w0 = wt0[ci], w1 = wt1[ci];                                     \
        float fx = (v.x - pc.x) * pc.y, fy = (v.y - pc.x) * pc.y;              \
        float fz = (v.z - pc.x) * pc.y, fw = (v.w - pc.x) * pc.y;              \
        acc0.x = fmaf(w0.x, fx, acc0.x); acc0.y = fmaf(w0.x, fy, acc0.y);      \
        acc0.z = fmaf(w0.x, fz, acc0.z); acc0.w = fmaf(w0.x, fw, acc0.w);      \
        acc1.x = fmaf(w0.y, fx, acc1.x); acc1.y = fmaf(w0.y, fy, acc1.y);      \
        acc1.z = fmaf(w0.y, fz, acc1.z); acc1.w = fmaf(w0.y, fw, acc1.w);      \
        acc2.x = fmaf(w0.z, fx, acc2.x); acc2.y = fmaf(w0.z, fy, acc2.y);      \
        acc2.z = fmaf(w0.z, fz, acc2.z); acc2.w = fmaf(w0.z, fw, acc2.w);      \
        acc3.x = fmaf(w0.w, fx, acc3.x); acc3.y = fmaf(w0.w, fy, acc3.y);      \
        acc3.z = fmaf(w0.w, fz, acc3.z); acc3.w = fmaf(w0.w, fw, acc3.w);      \
        acc4.x = fmaf(w1.x, fx, acc4.x); acc4.y = fmaf(w1.x, fy, acc4.y);      \
        acc4.z = fmaf(w1.x, fz, acc4.z); acc4.w = fmaf(w1.x, fw, acc4.w);      \
        acc5.x = fmaf(w1.y, fx, acc5.x); acc5.y = fmaf(w1.y, fy, acc5.y);      \
        acc5.z = fmaf(w1.y, fz, acc5.z); acc5.w = fmaf(w1.y, fw, acc5.w);      \
        acc6.x = fmaf(w1.z, fx, acc6.x); acc6.y = fmaf(w1.z, fy, acc6.y);      \
        acc6.z = fmaf(w1.z, fz, acc6.z); acc6.w = fmaf(w1.z, fw, acc6.w);      \
        acc7.x = fmaf(w1.w, fx, acc7.x); acc7.y = fmaf(w1.w, fy, acc7.y);      \
        acc7.z = fmaf(w1.w, fz, acc7.z); acc7.w = fmaf(w1.w, fw, acc7.w);      \
    }

    float4 buf[16];
#pragma unroll
    for (int j = 0; j < 16; ++j) buf[j] = px[(size_t)j * Q];
    for (int c = 0; c + 16 < NCH; c += 16) {   // c = 0, 16, 32
        float4 nb[16];
#pragma unroll
        for (int j = 0; j < 16; ++j) nb[j] = px[(size_t)(c + 16 + j) * Q];
        __builtin_amdgcn_sched_barrier(0);
#pragma unroll
        for (int j = 0; j < 16; ++j) PROC(buf[j], c + j);
#pragma unroll
        for (int j = 0; j < 16; ++j) buf[j] = nb[j];
    }
#pragma unroll
    for (int j = 0; j < 16; ++j) PROC(buf[j], 48 + j);
#undef PROC

    float4* out4 = (float4*)out + (size_t)img * NB * Q + q;
    float tmin[NB], tmax[NB];
    float4 accs[NB] = {acc0, acc1, acc2, acc3, acc4, acc5, acc6, acc7};
#pragma unroll
    for (int n = 0; n < NB; ++n) {
        float4 a = accs[n];
        float4 y;
        y.x = fmaxf(a.x * 255.f, 0.f);
        y.y = fmaxf(a.y * 255.f, 0.f);
        y.z = fmaxf(a.z * 255.f, 0.f);
        y.w = fmaxf(a.w * 255.f, 0.f);
        out4[(size_t)n * Q] = y;
        tmin[n] = fminf(fminf(y.x, y.y), fminf(y.z, y.w));
        tmax[n] = fmaxf(fmaxf(y.x, y.y), fmaxf(y.z, y.w));
    }
#pragma unroll
    for (int n = 0; n < NB; ++n) {
        for (int o = 32; o; o >>= 1) {
            tmin[n] = fminf(tmin[n], __shfl_down(tmin[n], o));
            tmax[n] = fmaxf(tmax[n], __shfl_down(tmax[n], o));
        }
    }
    if ((t & 63) == 0) {
#pragma unroll
        for (int n = 0; n < NB; ++n) {
            // nonneg floats: int ordering == float ordering
            atomicMin((int*)&ws[WS_PMIN + img * NB + n], __float_as_int(tmin[n]));
            atomicMax((int*)&ws[WS_PMAX + img * NB + n], __float_as_int(tmax[n]));
        }
    }
}

// K6: in-place per-(i,n) min-max normalize * 255.  grid 1024, block 256.
__global__ __launch_bounds__(256) void norm_out(float* __restrict__ out,
                                                const float* __restrict__ ws) {
    int pair = blockIdx.x >> 4;
    int t = threadIdx.x;
    float mnp = ws[WS_PMIN + pair];
    float rng = ws[WS_PMAX + pair] - mnp;
    float4* p = (float4*)out + (size_t)pair * (HW_N / 4) + (size_t)(blockIdx.x & 15) * 1024;
    if (rng != 0.f) {
        float inv = 255.f / rng;
#pragma unroll
        for (int k = 0; k < 4; ++k) {
            float4 v = p[k * 256 + t];
            v.x = (v.x - mnp) * inv;
            v.y = (v.y - mnp) * inv;
            v.z = (v.z - mnp) * inv;
            v.w = (v.w - mnp) * inv;
            p[k * 256 + t] = v;
        }
    } else {
        float4 z = make_float4(0.f, 0.f, 0.f, 0.f);
#pragma unroll
        for (int k = 0; k < 4; ++k) p[k * 256 + t] = z;
    }
}

extern "C" void kernel_launch(void* const* d_in, const int* in_sizes, int n_in,
                              void* d_out, int out_size, void* d_ws, size_t ws_size,
                              hipStream_t stream) {
    const float* x = (const float*)d_in[0];
    float* out = (float*)d_out;
    float* ws = (float*)d_ws;
    band_stats<<<NBAND, 1024, 0, stream>>>(x, ws);
    image_otsu<<<NB, 256, 0, stream>>>(ws);
    band_otsu_pfg<<<NBAND, 1024, 0, stream>>>(x, ws);
    compute_w<<<1, 512, 0, stream>>>(ws);
    einsum_relu<<<512, 256, 0, stream>>>(x, ws, out);
    norm_out<<<1024, 256, 0, stream>>>(out, ws);
}